// Round 15
// baseline (2282.766 us; speedup 1.0000x reference)
//
#include <hip/hip_runtime.h>
#include <math.h>

#define B_ 512
#define S_ 500
#define NQ1_ 10001
#define NQA1_ 20001
#define BS_ (B_ * S_)

typedef float v2f __attribute__((ext_vector_type(2)));
static __device__ __forceinline__ v2f pkfma(v2f a, v2f b, v2f c) {
    return __builtin_elementwise_fma(a, b, c);
}

// dot2 on packed bf16 pairs: returns a.lo*b.lo + a.hi*b.hi + c
static __device__ __forceinline__ float dot2bf(unsigned int a, unsigned int b, float c) {
#if __has_builtin(__builtin_amdgcn_fdot2_f32_bf16)
    typedef __bf16 bf16x2_t __attribute__((ext_vector_type(2)));
    bf16x2_t av, bv;
    __builtin_memcpy(&av, &a, sizeof(av));
    __builtin_memcpy(&bv, &b, sizeof(bv));
    return __builtin_amdgcn_fdot2_f32_bf16(av, bv, c, false);
#else
    float a0 = __uint_as_float(a << 16);
    float a1 = __uint_as_float(a & 0xFFFF0000u);
    float b0 = __uint_as_float(b << 16);
    float b1 = __uint_as_float(b & 0xFFFF0000u);
    return fmaf(a1, b1, fmaf(a0, b0, c));
#endif
}

// ---------------------------------------------------------------------------
// Fused prep: WeT, WaT, MkT, WsqT transposes + WsrQ bf16 pack, COALESCED
// z-phase layout: WsrQ[(d2g*128 + j)*4 + s] = bf16(Ws[j][8*d2g+2*s]) |
// bf16(Ws[j][8*d2g+2*s+1])<<16, d2g<32, j<128, s<4.
// ---------------------------------------------------------------------------
__global__ __launch_bounds__(256) void prep_kernel(
    const float* __restrict__ We, const float* __restrict__ Wa,
    const float* __restrict__ Mk, const float* __restrict__ Ws,
    float* __restrict__ WeT, float* __restrict__ WaT,
    float* __restrict__ MkT, float* __restrict__ WsqT,
    unsigned int* __restrict__ WsrQ)
{
    int idx = blockIdx.x * 256 + threadIdx.x;
    if (idx < 65536) {
        int r = idx >> 8, c = idx & 255;
        WeT[c * 256 + r] = We[r * 256 + c];
        return;
    }
    idx -= 65536;
    if (idx < 65536) {
        int r = idx >> 8, c = idx & 255;
        WaT[c * 256 + r] = Wa[r * 256 + c];
        return;
    }
    idx -= 65536;
    if (idx < 16384) {
        int r = idx >> 7, c = idx & 127;
        MkT[c * 128 + r] = Mk[r * 128 + c];
        return;
    }
    idx -= 16384;
    if (idx < 16384) {
        int r = idx >> 7, c = idx & 127;
        WsqT[c * 128 + r] = Ws[r * 384 + 256 + c];
        return;
    }
    idx -= 16384;
    if (idx < 16384) {
        int s = idx & 3;
        int j = (idx >> 2) & 127;
        int d2g = idx >> 9;
        int dd0 = 8 * d2g + 2 * s;
        unsigned int b0 = __float_as_uint(Ws[j * 384 + dd0]);
        unsigned int b1 = __float_as_uint(Ws[j * 384 + dd0 + 1]);
        WsrQ[idx] = ((b0 + 0x8000u) >> 16) | ((b1 + 0x8000u) & 0xFFFF0000u);
    }
}

// ---------------------------------------------------------------------------
// Per-q-index precompute: Wsm = softmax(q@Mk.T), Sq = q@Ws_q.T, dq = tanh(q@Wd+bd)
// ---------------------------------------------------------------------------
__global__ __launch_bounds__(64) void kq_kernel(
    const float* __restrict__ q_embed, const float* __restrict__ MkT,
    const float* __restrict__ WsqT, const float* __restrict__ Wd,
    const float* __restrict__ bdp,
    float* __restrict__ Wsm, float* __restrict__ Sq, float* __restrict__ dqv)
{
    int i0 = blockIdx.x * 8;
    int l = threadIdx.x;  // 0..63 -> j = 2l, 2l+1
    __shared__ float qlds[8][128];

#pragma unroll
    for (int r = 0; r < 8; ++r) {
        int i = i0 + r;
        v2f qv = { 0.f, 0.f };
        if (i < NQ1_) qv = *reinterpret_cast<const v2f*>(&q_embed[i * 128 + 2 * l]);
        *reinterpret_cast<v2f*>(&qlds[r][2 * l]) = qv;
    }
    __syncthreads();

    v2f lg[8], sq[8];
#pragma unroll
    for (int r = 0; r < 8; ++r) { lg[r] = (v2f){0.f, 0.f}; sq[r] = (v2f){0.f, 0.f}; }

    for (int k = 0; k < 128; ++k) {
        v2f mk = *reinterpret_cast<const v2f*>(&MkT[k * 128 + 2 * l]);
        v2f wq = *reinterpret_cast<const v2f*>(&WsqT[k * 128 + 2 * l]);
#pragma unroll
        for (int r = 0; r < 8; ++r) {
            float q = qlds[r][k];
            v2f q2 = { q, q };
            lg[r] = pkfma(q2, mk, lg[r]);
            sq[r] = pkfma(q2, wq, sq[r]);
        }
    }

    v2f wd2 = *reinterpret_cast<const v2f*>(&Wd[2 * l]);
    float bd = bdp[0];

#pragma unroll
    for (int r = 0; r < 8; ++r) {
        int i = i0 + r;
        float m = fmaxf(lg[r].x, lg[r].y);
        for (int off = 32; off; off >>= 1) m = fmaxf(m, __shfl_xor(m, off));
        float ex0 = expf(lg[r].x - m), ex1 = expf(lg[r].y - m);
        float s = ex0 + ex1;
        for (int off = 32; off; off >>= 1) s += __shfl_xor(s, off);
        float inv = 1.f / s;
        if (i < NQ1_) {
            v2f o = { ex0 * inv, ex1 * inv };
            *reinterpret_cast<v2f*>(&Wsm[i * 128 + 2 * l]) = o;
            *reinterpret_cast<v2f*>(&Sq[i * 128 + 2 * l]) = sq[r];
        }
        float dd = qlds[r][2 * l] * wd2.x + qlds[r][2 * l + 1] * wd2.y;
        for (int off = 32; off; off >>= 1) dd += __shfl_xor(dd, off);
        if (l == 0 && i < NQ1_) dqv[i] = tanhf(dd + bd);
    }
}

// ---------------------------------------------------------------------------
// Per-qa-index precompute: EA[i][d] = (sigmoid(..)_d, tanh(..)_d) interleaved.
// ---------------------------------------------------------------------------
__global__ __launch_bounds__(128) void kqa_kernel(
    const float* __restrict__ qa_embed, const float* __restrict__ WeT,
    const float* __restrict__ WaT, const float* __restrict__ be,
    const float* __restrict__ ba, float* __restrict__ EA)
{
    int i0 = blockIdx.x * 8;
    int l = threadIdx.x;  // 0..127 -> d = 2l, 2l+1
    __shared__ float qlds[8][256];

#pragma unroll
    for (int r = 0; r < 8; ++r) {
        int i = i0 + r;
        v2f qv = { 0.f, 0.f };
        if (i < NQA1_) qv = *reinterpret_cast<const v2f*>(&qa_embed[i * 256 + 2 * l]);
        *reinterpret_cast<v2f*>(&qlds[r][2 * l]) = qv;
    }
    __syncthreads();

    v2f be2 = *reinterpret_cast<const v2f*>(&be[2 * l]);
    v2f ba2 = *reinterpret_cast<const v2f*>(&ba[2 * l]);
    v2f zE[8], zA[8];
#pragma unroll
    for (int r = 0; r < 8; ++r) { zE[r] = be2; zA[r] = ba2; }

    for (int k = 0; k < 256; ++k) {
        v2f we2 = *reinterpret_cast<const v2f*>(&WeT[k * 256 + 2 * l]);
        v2f wa2 = *reinterpret_cast<const v2f*>(&WaT[k * 256 + 2 * l]);
#pragma unroll
        for (int r = 0; r < 8; ++r) {
            float q = qlds[r][k];
            v2f q2 = { q, q };
            zE[r] = pkfma(q2, we2, zE[r]);
            zA[r] = pkfma(q2, wa2, zA[r]);
        }
    }
#pragma unroll
    for (int r = 0; r < 8; ++r) {
        int i = i0 + r;
        if (i < NQA1_) {
            float4 o;
            o.x = 1.f / (1.f + expf(-zE[r].x));
            o.y = tanhf(zA[r].x);
            o.z = 1.f / (1.f + expf(-zE[r].y));
            o.w = tanhf(zA[r].y);
            *reinterpret_cast<float4*>(&EA[(size_t)(i * 256 + 2 * l) * 2]) = o;
        }
    }
}

// ---------------------------------------------------------------------------
// Recurrence v10 = round-14 structure, with the step-phase w-broadcast moved
// from the LDS pipe to the VECTOR-MEMORY pipe:
//  - w read directly from Wsm (global) at a per-p-half wave-uniform address:
//    the TA collapses each dwordx4 to 1-2 cache-line requests broadcast to
//    the wave (L1-hot row). Round 14 spent 16 waves x 16 ds_read_b128 x
//    12cyc ~ 3072 cyc/CU/step (62% of runtime) on this broadcast in LDS.
//  - wbuf + staging deleted; LDS = rbufB only (16.6 KB).
//  - qid register ring (4-deep, mirrors EA ring) keeps the w address known
//    4 steps ahead; unrolled 4-step body lets the compiler pipeline loads.
//  - z-phase identical to r14 (dot2-bf16, coalesced WsrQ, bf16 rbuf).
//  - NOT the failed r10 path: these are VECTOR loads (TA broadcast), not
//    readfirstlane+s_load (SGPR-capacity serialization).
// Plain __launch_bounds__(512): occupancy attrs caused 64-reg spill (r4-6);
// VGPR must stay <=128 (r10/r11's 136 halved residency).
// ---------------------------------------------------------------------------
__global__ __launch_bounds__(512)
void rec_kernel(
    const int* __restrict__ q_data, const int* __restrict__ qa_data,
    const float* __restrict__ Mv0,
    const float* __restrict__ Wsm, const float* __restrict__ Sq,
    const float* __restrict__ dqv, const float* __restrict__ EA,
    const unsigned int* __restrict__ WsrQ, const float* __restrict__ bs,
    const float* __restrict__ Wab, const float* __restrict__ bab,
    float* __restrict__ out)
{
    const int b = blockIdx.x;
    const int tid = threadIdx.x;
    const int d = tid >> 1;        // memory column (0..255)
    const int p = tid & 1;         // m-half (0..1)
    const int wv = tid >> 6;       // wave 0..7
    const int l = tid & 63;        // lane; owns j = l and l+64 in z-phase

    __shared__ __align__(16) unsigned short rbufB[2][16][256];  // 16 KB (bf16)

    const int* qrow = q_data + b * S_;
    const int* qarow = qa_data + b * S_;

    // Mv half-column in registers (rows p*64 .. p*64+63)
    v2f Mv2[32];
#pragma unroll
    for (int k = 0; k < 32; ++k) {
        Mv2[k].x = Mv0[(p * 64 + 2 * k) * 256 + d];
        Mv2[k].y = Mv0[(p * 64 + 2 * k + 1) * 256 + d];
    }

    const float bs0 = bs[l], bs1 = bs[l + 64];
    const float wab0 = Wab[l], wab1 = Wab[l + 64];
    const float babv = bab[0];

    // ring warmup: ear[u]/qir[u] for t=u; idr[u] = qa id for t=u+4
    v2f ear[4];
    int idr[4], qir[4];
#pragma unroll
    for (int u = 0; u < 4; ++u) {
        ear[u] = *reinterpret_cast<const v2f*>(&EA[((size_t)qarow[u] * 256 + d) * 2]);
        idr[u] = qarow[4 + u];
        qir[u] = qrow[u];
    }

    const uint4* WQ4 = reinterpret_cast<const uint4*>(WsrQ);

    for (int e = 0; e < 32; ++e) {
        const int eb = e & 1;

        // ---- 16 barrier-free steps; w via vector-memory broadcast ----
        for (int kg = 0; kg < 4; ++kg) {
#pragma unroll
            for (int u = 0; u < 4; ++u) {
                const int k = kg * 4 + u;
                const int t = e * 16 + k;
                const float e_d = ear[u].x;
                const float a_d = ear[u].y;
                const int qs = qir[u];
                // refill rings (ea for t+4, qa-id for t+8, q-id for t+4)
                {
                    int qa4 = idr[u];
                    ear[u] = *reinterpret_cast<const v2f*>(
                        &EA[((size_t)qa4 * 256 + d) * 2]);
                    int t8 = t + 8; if (t8 > S_ - 1) t8 = S_ - 1;
                    idr[u] = qarow[t8];
                    int t4 = t + 4; if (t4 > S_ - 1) t4 = S_ - 1;
                    qir[u] = qrow[t4];
                }
                const v2f ne2 = { -e_d, -e_d };
                const v2f a2 = { a_d, a_d };
                v2f rd0 = { 0.f, 0.f }, rd1 = { 0.f, 0.f };
                const float4* wp = reinterpret_cast<const float4*>(
                    Wsm + ((size_t)qs << 7) + (p << 6));   // L1-hot broadcast
#pragma unroll
                for (int mq = 0; mq < 16; ++mq) {
                    float4 w4 = wp[mq];                   // global_load_dwordx4
                    v2f wA = { w4.x, w4.y };
                    v2f wB = { w4.z, w4.w };
                    v2f mA = Mv2[2 * mq];
                    v2f mB = Mv2[2 * mq + 1];
                    v2f tA = pkfma(ne2, mA, a2);          // a - e*m
                    v2f tB = pkfma(ne2, mB, a2);
                    rd0 = pkfma(wA, mA, rd0);             // read += w*m (old)
                    rd1 = pkfma(wB, mB, rd1);
                    Mv2[2 * mq]     = pkfma(wA, tA, mA);  // m' = m + w*(a-e*m)
                    Mv2[2 * mq + 1] = pkfma(wB, tB, mB);
                }
                v2f rs = rd0 + rd1;
                float rh = rs.x + rs.y;
                float rfull = rh + __shfl_xor(rh, 1);     // pair-sum (DPP)
                if (p == 0)
                    rbufB[eb][k][d] =
                        (unsigned short)((__float_as_uint(rfull) + 0x8000u) >> 16);
            }
        }

        // ---- z-phase inputs (wave wv owns t = e*16 + wv*2 + c, c in {0,1}) ----
        float sq0v[2], sq1v[2], dqvv[2];
#pragma unroll
        for (int c = 0; c < 2; ++c) {
            int tt = e * 16 + wv * 2 + c; if (tt > S_ - 1) tt = S_ - 1;
            int qtc = qrow[tt];
            sq0v[c] = Sq[(size_t)qtc * 128 + l];
            sq1v[c] = Sq[(size_t)qtc * 128 + 64 + l];
            dqvv[c] = dqv[qtc];
        }

        __syncthreads();   // the ONE barrier of this epoch

        // ---- z-phase: z[t][j] = sum_d rbuf[t][d]*Wsr[j][d], dot2 on bf16,
        //      coalesced Wsr loads (lane stride 16B) ----
        float zA0 = 0.f, zA1 = 0.f;    // j = l,    t = tb, tb+1
        float zB0 = 0.f, zB1 = 0.f;    // j = l+64
        const int tb = wv * 2;
#pragma unroll 4
        for (int d2g = 0; d2g < 32; ++d2g) {
            uint4 wA = WQ4[d2g * 128 + l];        // coalesced
            uint4 wB = WQ4[d2g * 128 + l + 64];   // coalesced
            uint4 r0 = *reinterpret_cast<const uint4*>(&rbufB[eb][tb + 0][8 * d2g]);
            uint4 r1 = *reinterpret_cast<const uint4*>(&rbufB[eb][tb + 1][8 * d2g]);
            zA0 = dot2bf(r0.x, wA.x, zA0);
            zA0 = dot2bf(r0.y, wA.y, zA0);
            zA0 = dot2bf(r0.z, wA.z, zA0);
            zA0 = dot2bf(r0.w, wA.w, zA0);
            zB0 = dot2bf(r0.x, wB.x, zB0);
            zB0 = dot2bf(r0.y, wB.y, zB0);
            zB0 = dot2bf(r0.z, wB.z, zB0);
            zB0 = dot2bf(r0.w, wB.w, zB0);
            zA1 = dot2bf(r1.x, wA.x, zA1);
            zA1 = dot2bf(r1.y, wA.y, zA1);
            zA1 = dot2bf(r1.z, wA.z, zA1);
            zA1 = dot2bf(r1.w, wA.w, zA1);
            zB1 = dot2bf(r1.x, wB.x, zB1);
            zB1 = dot2bf(r1.y, wB.y, zB1);
            zB1 = dot2bf(r1.z, wB.z, zB1);
            zB1 = dot2bf(r1.w, wB.w, zB1);
        }
        float zjA[2] = { zA0, zA1 };
        float zjB[2] = { zB0, zB1 };
#pragma unroll
        for (int c = 0; c < 2; ++c) {
            float z0 = zjA[c] + sq0v[c] + bs0;
            float z1 = zjB[c] + sq1v[c] + bs1;
            z0 = fminf(fmaxf(z0, -15.f), 15.f);
            z1 = fminf(fmaxf(z1, -15.f), 15.f);
            float ex = __expf(2.f * z0);
            float ey = __expf(2.f * z1);
            float sv = ((ex - 1.f) / (ex + 1.f)) * wab0
                     + ((ey - 1.f) / (ey + 1.f)) * wab1;
            sv += __shfl_xor(sv, 32);
            sv += __shfl_xor(sv, 16);
            sv += __shfl_xor(sv, 8);
            sv += __shfl_xor(sv, 4);
            sv += __shfl_xor(sv, 2);
            sv += __shfl_xor(sv, 1);
            if (l == 0) {
                int tt = e * 16 + wv * 2 + c;
                if (tt < S_) {
                    float ab = sv + babv;
                    float dq = dqvv[c];
                    out[b * S_ + tt] = 3.f * ab - dq;
                    out[BS_ + b * S_ + tt] = ab;
                    out[2 * BS_ + b * S_ + tt] = dq;
                }
            }
        }
    }
}

// ---------------------------------------------------------------------------
extern "C" void kernel_launch(void* const* d_in, const int* in_sizes, int n_in,
                              void* d_out, int out_size, void* d_ws, size_t ws_size,
                              hipStream_t stream) {
    const int* q_data  = (const int*)d_in[0];
    const int* qa_data = (const int*)d_in[1];
    const float* Mk       = (const float*)d_in[3];
    const float* Mv0      = (const float*)d_in[4];
    const float* q_embed  = (const float*)d_in[5];
    const float* qa_embed = (const float*)d_in[6];
    const float* We  = (const float*)d_in[7];
    const float* be  = (const float*)d_in[8];
    const float* Wa  = (const float*)d_in[9];
    const float* ba  = (const float*)d_in[10];
    const float* Ws  = (const float*)d_in[11];
    const float* bs  = (const float*)d_in[12];
    const float* Wab = (const float*)d_in[13];
    const float* bab = (const float*)d_in[14];
    const float* Wd  = (const float*)d_in[15];
    const float* bd  = (const float*)d_in[16];
    float* out = (float*)d_out;

    float* ws   = (float*)d_ws;
    float* WeT  = ws;                       // 65536
    float* WaT  = WeT  + 65536;             // 65536
    float* MkT  = WaT  + 65536;             // 16384
    float* WsqT = MkT  + 16384;             // 16384
    unsigned int* WsrQ = (unsigned int*)(WsqT + 16384);  // 16384 u32
    float* Wsm  = (float*)(WsrQ + 16384);   // NQ1_*128
    float* Sq   = Wsm  + NQ1_ * 128;        // NQ1_*128
    float* dqv  = Sq   + NQ1_ * 128;        // 10016
    float* EA   = dqv  + 10016;             // NQA1_*512 (float2 interleaved)
    // total ~= 52 MB (identical footprint to the passing rounds)

    prep_kernel<<<704, 256, 0, stream>>>(We, Wa, Mk, Ws, WeT, WaT, MkT, WsqT, WsrQ);
    kq_kernel<<<(NQ1_ + 7) / 8, 64, 0, stream>>>(q_embed, MkT, WsqT, Wd, bd, Wsm, Sq, dqv);
    kqa_kernel<<<(NQA1_ + 7) / 8, 128, 0, stream>>>(qa_embed, WeT, WaT, be, ba, EA);
    rec_kernel<<<B_, 512, 0, stream>>>(q_data, qa_data, Mv0, Wsm, Sq, dqv, EA,
                                       WsrQ, bs, Wab, bab, out);
}

// Round 16
// 1006.500 us; speedup vs baseline: 2.2680x; 2.2680x over previous
//
#include <hip/hip_runtime.h>
#include <math.h>

#define B_ 512
#define S_ 500
#define NQ1_ 10001
#define NQA1_ 20001
#define BS_ (B_ * S_)

typedef float v2f __attribute__((ext_vector_type(2)));
static __device__ __forceinline__ v2f pkfma(v2f a, v2f b, v2f c) {
    return __builtin_elementwise_fma(a, b, c);
}

// dot2 on packed bf16 pairs: returns a.lo*b.lo + a.hi*b.hi + c
static __device__ __forceinline__ float dot2bf(unsigned int a, unsigned int b, float c) {
#if __has_builtin(__builtin_amdgcn_fdot2_f32_bf16)
    typedef __bf16 bf16x2_t __attribute__((ext_vector_type(2)));
    bf16x2_t av, bv;
    __builtin_memcpy(&av, &a, sizeof(av));
    __builtin_memcpy(&bv, &b, sizeof(bv));
    return __builtin_amdgcn_fdot2_f32_bf16(av, bv, c, false);
#else
    float a0 = __uint_as_float(a << 16);
    float a1 = __uint_as_float(a & 0xFFFF0000u);
    float b0 = __uint_as_float(b << 16);
    float b1 = __uint_as_float(b & 0xFFFF0000u);
    return fmaf(a1, b1, fmaf(a0, b0, c));
#endif
}

// ---------------------------------------------------------------------------
// Fused prep: WeT, WaT, MkT, WsqT transposes + WsrQ bf16 pack, COALESCED
// z-phase layout: WsrQ[(d2g*128 + j)*4 + s] = bf16(Ws[j][8*d2g+2*s]) |
// bf16(Ws[j][8*d2g+2*s+1])<<16, d2g<32, j<128, s<4. Lane l reads uint4 at
// (d2g*128 + j) -> 16B lane stride (coalesced), d packed in u32 (dot2-ready).
// ---------------------------------------------------------------------------
__global__ __launch_bounds__(256) void prep_kernel(
    const float* __restrict__ We, const float* __restrict__ Wa,
    const float* __restrict__ Mk, const float* __restrict__ Ws,
    float* __restrict__ WeT, float* __restrict__ WaT,
    float* __restrict__ MkT, float* __restrict__ WsqT,
    unsigned int* __restrict__ WsrQ)
{
    int idx = blockIdx.x * 256 + threadIdx.x;
    if (idx < 65536) {
        int r = idx >> 8, c = idx & 255;
        WeT[c * 256 + r] = We[r * 256 + c];
        return;
    }
    idx -= 65536;
    if (idx < 65536) {
        int r = idx >> 8, c = idx & 255;
        WaT[c * 256 + r] = Wa[r * 256 + c];
        return;
    }
    idx -= 65536;
    if (idx < 16384) {
        int r = idx >> 7, c = idx & 127;
        MkT[c * 128 + r] = Mk[r * 128 + c];
        return;
    }
    idx -= 16384;
    if (idx < 16384) {
        int r = idx >> 7, c = idx & 127;
        WsqT[c * 128 + r] = Ws[r * 384 + 256 + c];
        return;
    }
    idx -= 16384;
    if (idx < 16384) {
        int s = idx & 3;
        int j = (idx >> 2) & 127;
        int d2g = idx >> 9;
        int dd0 = 8 * d2g + 2 * s;
        unsigned int b0 = __float_as_uint(Ws[j * 384 + dd0]);
        unsigned int b1 = __float_as_uint(Ws[j * 384 + dd0 + 1]);
        WsrQ[idx] = ((b0 + 0x8000u) >> 16) | ((b1 + 0x8000u) & 0xFFFF0000u);
    }
}

// ---------------------------------------------------------------------------
// Per-q-index precompute: Wsm = softmax(q@Mk.T), Sq = q@Ws_q.T, dq = tanh(q@Wd+bd)
// ---------------------------------------------------------------------------
__global__ __launch_bounds__(64) void kq_kernel(
    const float* __restrict__ q_embed, const float* __restrict__ MkT,
    const float* __restrict__ WsqT, const float* __restrict__ Wd,
    const float* __restrict__ bdp,
    float* __restrict__ Wsm, float* __restrict__ Sq, float* __restrict__ dqv)
{
    int i0 = blockIdx.x * 8;
    int l = threadIdx.x;  // 0..63 -> j = 2l, 2l+1
    __shared__ float qlds[8][128];

#pragma unroll
    for (int r = 0; r < 8; ++r) {
        int i = i0 + r;
        v2f qv = { 0.f, 0.f };
        if (i < NQ1_) qv = *reinterpret_cast<const v2f*>(&q_embed[i * 128 + 2 * l]);
        *reinterpret_cast<v2f*>(&qlds[r][2 * l]) = qv;
    }
    __syncthreads();

    v2f lg[8], sq[8];
#pragma unroll
    for (int r = 0; r < 8; ++r) { lg[r] = (v2f){0.f, 0.f}; sq[r] = (v2f){0.f, 0.f}; }

    for (int k = 0; k < 128; ++k) {
        v2f mk = *reinterpret_cast<const v2f*>(&MkT[k * 128 + 2 * l]);
        v2f wq = *reinterpret_cast<const v2f*>(&WsqT[k * 128 + 2 * l]);
#pragma unroll
        for (int r = 0; r < 8; ++r) {
            float q = qlds[r][k];
            v2f q2 = { q, q };
            lg[r] = pkfma(q2, mk, lg[r]);
            sq[r] = pkfma(q2, wq, sq[r]);
        }
    }

    v2f wd2 = *reinterpret_cast<const v2f*>(&Wd[2 * l]);
    float bd = bdp[0];

#pragma unroll
    for (int r = 0; r < 8; ++r) {
        int i = i0 + r;
        float m = fmaxf(lg[r].x, lg[r].y);
        for (int off = 32; off; off >>= 1) m = fmaxf(m, __shfl_xor(m, off));
        float ex0 = expf(lg[r].x - m), ex1 = expf(lg[r].y - m);
        float s = ex0 + ex1;
        for (int off = 32; off; off >>= 1) s += __shfl_xor(s, off);
        float inv = 1.f / s;
        if (i < NQ1_) {
            v2f o = { ex0 * inv, ex1 * inv };
            *reinterpret_cast<v2f*>(&Wsm[i * 128 + 2 * l]) = o;
            *reinterpret_cast<v2f*>(&Sq[i * 128 + 2 * l]) = sq[r];
        }
        float dd = qlds[r][2 * l] * wd2.x + qlds[r][2 * l + 1] * wd2.y;
        for (int off = 32; off; off >>= 1) dd += __shfl_xor(dd, off);
        if (l == 0 && i < NQ1_) dqv[i] = tanhf(dd + bd);
    }
}

// ---------------------------------------------------------------------------
// Per-qa-index precompute: EA[i][d] = (sigmoid(..)_d, tanh(..)_d) interleaved.
// ---------------------------------------------------------------------------
__global__ __launch_bounds__(128) void kqa_kernel(
    const float* __restrict__ qa_embed, const float* __restrict__ WeT,
    const float* __restrict__ WaT, const float* __restrict__ be,
    const float* __restrict__ ba, float* __restrict__ EA)
{
    int i0 = blockIdx.x * 8;
    int l = threadIdx.x;  // 0..127 -> d = 2l, 2l+1
    __shared__ float qlds[8][256];

#pragma unroll
    for (int r = 0; r < 8; ++r) {
        int i = i0 + r;
        v2f qv = { 0.f, 0.f };
        if (i < NQA1_) qv = *reinterpret_cast<const v2f*>(&qa_embed[i * 256 + 2 * l]);
        *reinterpret_cast<v2f*>(&qlds[r][2 * l]) = qv;
    }
    __syncthreads();

    v2f be2 = *reinterpret_cast<const v2f*>(&be[2 * l]);
    v2f ba2 = *reinterpret_cast<const v2f*>(&ba[2 * l]);
    v2f zE[8], zA[8];
#pragma unroll
    for (int r = 0; r < 8; ++r) { zE[r] = be2; zA[r] = ba2; }

    for (int k = 0; k < 256; ++k) {
        v2f we2 = *reinterpret_cast<const v2f*>(&WeT[k * 256 + 2 * l]);
        v2f wa2 = *reinterpret_cast<const v2f*>(&WaT[k * 256 + 2 * l]);
#pragma unroll
        for (int r = 0; r < 8; ++r) {
            float q = qlds[r][k];
            v2f q2 = { q, q };
            zE[r] = pkfma(q2, we2, zE[r]);
            zA[r] = pkfma(q2, wa2, zA[r]);
        }
    }
#pragma unroll
    for (int r = 0; r < 8; ++r) {
        int i = i0 + r;
        if (i < NQA1_) {
            float4 o;
            o.x = 1.f / (1.f + expf(-zE[r].x));
            o.y = tanhf(zA[r].x);
            o.z = 1.f / (1.f + expf(-zE[r].y));
            o.w = tanhf(zA[r].y);
            *reinterpret_cast<float4*>(&EA[(size_t)(i * 256 + 2 * l) * 2]) = o;
        }
    }
}

// ---------------------------------------------------------------------------
// Recurrence (round-14 verified best): 512 thr, half-column per thread, DPP
// pair-sum, 1 barrier/epoch, dot2-bf16 z-phase with COALESCED Wsr.
//  - w rows per-epoch LDS double-buffered; ds_read_b128 broadcast is the
//    right feed path: r10 (s_load, SGPR capacity), r13 (uncoalesced rows),
//    r15 (vmem uniform broadcast, per-step VMEM latency chain) all regressed.
//  - rbuf stored bf16 [2][16][256] u16; z-phase rbuf broadcasts 64
//    b128/wave/epoch.
//  - WsrQ layout [(d2g*128+j)*4+s]: lane l loads uint4 at d2g*128+l and
//    d2g*128+l+64 -> 16B lane stride, fully coalesced.
//  - v_dot2_f32_bf16: 2 MACs/op, zero unpack.
// Plain __launch_bounds__(512): occupancy attrs caused 64-reg spill (r4-6);
// VGPR must stay <=128 (r10/r11's 136 halved residency).
// ---------------------------------------------------------------------------
__global__ __launch_bounds__(512)
void rec_kernel(
    const int* __restrict__ q_data, const int* __restrict__ qa_data,
    const float* __restrict__ Mv0,
    const float* __restrict__ Wsm, const float* __restrict__ Sq,
    const float* __restrict__ dqv, const float* __restrict__ EA,
    const unsigned int* __restrict__ WsrQ, const float* __restrict__ bs,
    const float* __restrict__ Wab, const float* __restrict__ bab,
    float* __restrict__ out)
{
    const int b = blockIdx.x;
    const int tid = threadIdx.x;
    const int d = tid >> 1;        // memory column (0..255)
    const int p = tid & 1;         // m-half (0..1)
    const int wv = tid >> 6;       // wave 0..7
    const int l = tid & 63;        // lane; owns j = l and l+64 in z-phase

    __shared__ __align__(16) float wbuf[2][16][132];            // 16.9 KB
    __shared__ __align__(16) unsigned short rbufB[2][16][256];  // 16 KB (bf16)

    const int* qrow = q_data + b * S_;
    const int* qarow = qa_data + b * S_;

    // Mv half-column in registers (rows p*64 .. p*64+63)
    v2f Mv2[32];
#pragma unroll
    for (int k = 0; k < 32; ++k) {
        Mv2[k].x = Mv0[(p * 64 + 2 * k) * 256 + d];
        Mv2[k].y = Mv0[(p * 64 + 2 * k + 1) * 256 + d];
    }

    const float bs0 = bs[l], bs1 = bs[l + 64];
    const float wab0 = Wab[l], wab1 = Wab[l + 64];
    const float babv = bab[0];

    const int r_s = tid >> 5;      // staging: row 0..15
    const int c_s = tid & 31;      // staging: float4 chunk 0..31
    const int dsto = c_s * 4 + ((c_s & 16) >> 2);  // +4 pad for upper half-row
    const int p68 = p * 68;

    // prologue: stage epoch-0 w rows
    {
        int qid = qrow[r_s];
        const float* wsrc = Wsm + (size_t)qid * 128 + c_s * 4;
        *reinterpret_cast<float4*>(&wbuf[0][r_s][dsto]) =
            *reinterpret_cast<const float4*>(wsrc);
    }
    // ring warmup: ear[u] = EA for t=u; idr[u] = qa id for t=u+4
    v2f ear[4];
    int idr[4];
#pragma unroll
    for (int u = 0; u < 4; ++u) {
        ear[u] = *reinterpret_cast<const v2f*>(&EA[((size_t)qarow[u] * 256 + d) * 2]);
        idr[u] = qarow[4 + u];
    }
    __syncthreads();

    const uint4* WQ4 = reinterpret_cast<const uint4*>(WsrQ);

    for (int e = 0; e < 32; ++e) {
        const int eb = e & 1;

        // ---- stage issue: w rows for epoch e+1 ----
        int t1 = (e + 1) * 16 + r_s; if (t1 > 499) t1 = 499;
        const float* wsrc = Wsm + (size_t)qrow[t1] * 128 + c_s * 4;
        float4 sw0 = *reinterpret_cast<const float4*>(wsrc);

        // ---- 16 barrier-free steps ----
        for (int kg = 0; kg < 4; ++kg) {
#pragma unroll
            for (int u = 0; u < 4; ++u) {
                const int k = kg * 4 + u;
                const int t = e * 16 + k;
                const float e_d = ear[u].x;
                const float a_d = ear[u].y;
                // refill rings (ea for t+4, qa-id for t+8)
                {
                    int qa4 = idr[u];
                    ear[u] = *reinterpret_cast<const v2f*>(
                        &EA[((size_t)qa4 * 256 + d) * 2]);
                    int t8 = t + 8; if (t8 > S_ - 1) t8 = S_ - 1;
                    idr[u] = qarow[t8];
                }
                const v2f ne2 = { -e_d, -e_d };
                const v2f a2 = { a_d, a_d };
                v2f rd0 = { 0.f, 0.f }, rd1 = { 0.f, 0.f };
                const float4* wp = reinterpret_cast<const float4*>(&wbuf[eb][k][p68]);
#pragma unroll
                for (int mq = 0; mq < 16; ++mq) {
                    float4 w4 = wp[mq];                   // 2-addr broadcast b128
                    v2f wA = { w4.x, w4.y };
                    v2f wB = { w4.z, w4.w };
                    v2f mA = Mv2[2 * mq];
                    v2f mB = Mv2[2 * mq + 1];
                    v2f tA = pkfma(ne2, mA, a2);          // a - e*m
                    v2f tB = pkfma(ne2, mB, a2);
                    rd0 = pkfma(wA, mA, rd0);             // read += w*m (old)
                    rd1 = pkfma(wB, mB, rd1);
                    Mv2[2 * mq]     = pkfma(wA, tA, mA);  // m' = m + w*(a-e*m)
                    Mv2[2 * mq + 1] = pkfma(wB, tB, mB);
                }
                v2f rs = rd0 + rd1;
                float rh = rs.x + rs.y;
                float rfull = rh + __shfl_xor(rh, 1);     // pair-sum (DPP)
                if (p == 0)
                    rbufB[eb][k][d] =
                        (unsigned short)((__float_as_uint(rfull) + 0x8000u) >> 16);
            }
        }

        // ---- z-phase inputs (wave wv owns t = e*16 + wv*2 + c, c in {0,1}) ----
        float sq0v[2], sq1v[2], dqvv[2];
#pragma unroll
        for (int c = 0; c < 2; ++c) {
            int tt = e * 16 + wv * 2 + c; if (tt > S_ - 1) tt = S_ - 1;
            int qtc = qrow[tt];
            sq0v[c] = Sq[(size_t)qtc * 128 + l];
            sq1v[c] = Sq[(size_t)qtc * 128 + 64 + l];
            dqvv[c] = dqv[qtc];
        }

        // ---- stage write + the ONE barrier of this epoch ----
        *reinterpret_cast<float4*>(&wbuf[eb ^ 1][r_s][dsto]) = sw0;
        __syncthreads();

        // ---- z-phase: z[t][j] = sum_d rbuf[t][d]*Wsr[j][d], dot2 on bf16,
        //      coalesced Wsr loads (lane stride 16B) ----
        float zA0 = 0.f, zA1 = 0.f;    // j = l,    t = tb, tb+1
        float zB0 = 0.f, zB1 = 0.f;    // j = l+64
        const int tb = wv * 2;
#pragma unroll 4
        for (int d2g = 0; d2g < 32; ++d2g) {
            uint4 wA = WQ4[d2g * 128 + l];        // coalesced
            uint4 wB = WQ4[d2g * 128 + l + 64];   // coalesced
            uint4 r0 = *reinterpret_cast<const uint4*>(&rbufB[eb][tb + 0][8 * d2g]);
            uint4 r1 = *reinterpret_cast<const uint4*>(&rbufB[eb][tb + 1][8 * d2g]);
            zA0 = dot2bf(r0.x, wA.x, zA0);
            zA0 = dot2bf(r0.y, wA.y, zA0);
            zA0 = dot2bf(r0.z, wA.z, zA0);
            zA0 = dot2bf(r0.w, wA.w, zA0);
            zB0 = dot2bf(r0.x, wB.x, zB0);
            zB0 = dot2bf(r0.y, wB.y, zB0);
            zB0 = dot2bf(r0.z, wB.z, zB0);
            zB0 = dot2bf(r0.w, wB.w, zB0);
            zA1 = dot2bf(r1.x, wA.x, zA1);
            zA1 = dot2bf(r1.y, wA.y, zA1);
            zA1 = dot2bf(r1.z, wA.z, zA1);
            zA1 = dot2bf(r1.w, wA.w, zA1);
            zB1 = dot2bf(r1.x, wB.x, zB1);
            zB1 = dot2bf(r1.y, wB.y, zB1);
            zB1 = dot2bf(r1.z, wB.z, zB1);
            zB1 = dot2bf(r1.w, wB.w, zB1);
        }
        float zjA[2] = { zA0, zA1 };
        float zjB[2] = { zB0, zB1 };
#pragma unroll
        for (int c = 0; c < 2; ++c) {
            float z0 = zjA[c] + sq0v[c] + bs0;
            float z1 = zjB[c] + sq1v[c] + bs1;
            z0 = fminf(fmaxf(z0, -15.f), 15.f);
            z1 = fminf(fmaxf(z1, -15.f), 15.f);
            float ex = __expf(2.f * z0);
            float ey = __expf(2.f * z1);
            float sv = ((ex - 1.f) / (ex + 1.f)) * wab0
                     + ((ey - 1.f) / (ey + 1.f)) * wab1;
            sv += __shfl_xor(sv, 32);
            sv += __shfl_xor(sv, 16);
            sv += __shfl_xor(sv, 8);
            sv += __shfl_xor(sv, 4);
            sv += __shfl_xor(sv, 2);
            sv += __shfl_xor(sv, 1);
            if (l == 0) {
                int tt = e * 16 + wv * 2 + c;
                if (tt < S_) {
                    float ab = sv + babv;
                    float dq = dqvv[c];
                    out[b * S_ + tt] = 3.f * ab - dq;
                    out[BS_ + b * S_ + tt] = ab;
                    out[2 * BS_ + b * S_ + tt] = dq;
                }
            }
        }
    }
}

// ---------------------------------------------------------------------------
extern "C" void kernel_launch(void* const* d_in, const int* in_sizes, int n_in,
                              void* d_out, int out_size, void* d_ws, size_t ws_size,
                              hipStream_t stream) {
    const int* q_data  = (const int*)d_in[0];
    const int* qa_data = (const int*)d_in[1];
    const float* Mk       = (const float*)d_in[3];
    const float* Mv0      = (const float*)d_in[4];
    const float* q_embed  = (const float*)d_in[5];
    const float* qa_embed = (const float*)d_in[6];
    const float* We  = (const float*)d_in[7];
    const float* be  = (const float*)d_in[8];
    const float* Wa  = (const float*)d_in[9];
    const float* ba  = (const float*)d_in[10];
    const float* Ws  = (const float*)d_in[11];
    const float* bs  = (const float*)d_in[12];
    const float* Wab = (const float*)d_in[13];
    const float* bab = (const float*)d_in[14];
    const float* Wd  = (const float*)d_in[15];
    const float* bd  = (const float*)d_in[16];
    float* out = (float*)d_out;

    float* ws   = (float*)d_ws;
    float* WeT  = ws;                       // 65536
    float* WaT  = WeT  + 65536;             // 65536
    float* MkT  = WaT  + 65536;             // 16384
    float* WsqT = MkT  + 16384;             // 16384
    unsigned int* WsrQ = (unsigned int*)(WsqT + 16384);  // 16384 u32
    float* Wsm  = (float*)(WsrQ + 16384);   // NQ1_*128
    float* Sq   = Wsm  + NQ1_ * 128;        // NQ1_*128
    float* dqv  = Sq   + NQ1_ * 128;        // 10016
    float* EA   = dqv  + 10016;             // NQA1_*512 (float2 interleaved)
    // total ~= 52 MB (identical footprint to the passing rounds)

    prep_kernel<<<704, 256, 0, stream>>>(We, Wa, Mk, Ws, WeT, WaT, MkT, WsqT, WsrQ);
    kq_kernel<<<(NQ1_ + 7) / 8, 64, 0, stream>>>(q_embed, MkT, WsqT, Wd, bd, Wsm, Sq, dqv);
    kqa_kernel<<<(NQA1_ + 7) / 8, 128, 0, stream>>>(qa_embed, WeT, WaT, be, ba, EA);
    rec_kernel<<<B_, 512, 0, stream>>>(q_data, qa_data, Mv0, Wsm, Sq, dqv, EA,
                                       WsrQ, bs, Wab, bab, out);
}